// Round 11
// baseline (190.516 us; speedup 1.0000x reference)
//
#include <hip/hip_runtime.h>
#include <math.h>

#define NB 1024
#define NF 36
#define ED 256
#define NK 8
#define NN2 1296   // 36*36

typedef _Float16 f16;
typedef f16 f16x4 __attribute__((ext_vector_type(4)));
typedef f16 f16x8 __attribute__((ext_vector_type(8)));
typedef float f32x4 __attribute__((ext_vector_type(4)));

#define WXSTR 136     // f16 per Wx row (128 + 8 pad)
#define NFRAG 1536    // 3 row-tiles * 8 kc * 64 lanes, f16x8 each

// ---- ntn_main LDS (compact): Xh(rt0,1) | Xc2 | zero | Wxh0 | Wxh1 | v ----
// Xh rt2 tile is 75% zero rows -> 4 valid rows compact + 16B broadcast-zero.
// Wxh rows 36-47 are never consumed -> 36-row buffers; nt2 reads clamp.
#define XC2_OFF 16384                 // 8 kc * 16 lanes * 16B = 2048
#define ZB_OFF  18432                 // 16B zeros (broadcast reads)
#define WX0_OFF 18448                 // 36 * 136 * 2 = 9792
#define WX1_OFF (WX0_OFF + 9792)      // 28240
#define V_OFF   (WX1_OFF + 9792)      // 38032
#define SMEM_MAIN (V_OFF + (72 + 72 + 9 + 324) * 4)   // 39940; 4x <= 163840

// ---- prep_all LDS: VfH | VfL | partials  = 28672 B ----
#define PVH_OFF 0
#define PVL_OFF 8192
#define PP_OFF  16384
#define SMEM_PREP 28672

#define TWO_LOG2E 2.8853900817779268f
#define C1F (0.0625f * TWO_LOG2E)

__device__ __forceinline__ f32x4 mfma16(f16x8 a, f16x8 b, f32x4 c) {
    return __builtin_amdgcn_mfma_f32_16x16x32_f16(a, b, c, 0, 0, 0);
}

// Xh fragment address: frags 0-15 (rt0,1) linear; frags 16-23 (rt2) compact
// for l15<4, broadcast zero block for l15>=4.
__device__ __forceinline__ const f16x8* xfragp(const char* smem, int f, int lane) {
    const int l15 = lane & 15, q = (lane >> 4) & 3;
    int off;
    if (f < 16) off = (f * 64 + lane) * 16;
    else        off = (l15 < 4) ? (XC2_OFF + (((f - 16) * 16) + q * 4 + l15) * 16)
                                : ZB_OFF;
    return (const f16x8*)(smem + off);
}

// blocks [0,128): W fragment pack, one (k,ct) tile per block.
// blocks [128,1152): X fragment pack + v12 (unchanged from R10).
__global__ __launch_bounds__(256, 4) void prep_all(
    const float* __restrict__ W, f16x8* __restrict__ WfH,
    const float* __restrict__ texts, f16x8* __restrict__ XfH,
    const float* __restrict__ V1w, const float* __restrict__ V1b,
    const float* __restrict__ V2w, const float* __restrict__ V2b,
    const float* __restrict__ Wb, float* __restrict__ v12)
{
    extern __shared__ char psmem[];
    const int blk = blockIdx.x;
    const int t = threadIdx.x;
    const int wave = t >> 6, lane = t & 63;

    if (blk < 128) {   // ---- W pack: (k, ct) tile ----
        const int k = blk >> 4, ct = blk & 15;
        f16* Wl = (f16*)psmem;                    // [16][264] f16, scaled x16
        {
            const int r = t >> 4, seg = t & 15;
            const float* src = W + ((size_t)(k * 256 + ct * 16 + r)) * 256 + seg * 16;
            f16* d = Wl + r * 264 + seg * 16;
            #pragma unroll
            for (int j4 = 0; j4 < 4; ++j4) {
                float4 a = ((const float4*)src)[j4];
                d[j4 * 4 + 0] = (f16)(a.x * 16.0f);
                d[j4 * 4 + 1] = (f16)(a.y * 16.0f);
                d[j4 * 4 + 2] = (f16)(a.z * 16.0f);
                d[j4 * 4 + 3] = (f16)(a.w * 16.0f);
            }
        }
        __syncthreads();
        f16x8* dst = WfH + (size_t)(k * 16 + ct) * 8 * 64;
        #pragma unroll
        for (int e0 = 0; e0 < 2; ++e0) {
            const int e = t + e0 * 256;
            const int kc = e >> 6, el = e & 63, qd = el >> 4, l15 = el & 15;
            dst[e] = *(const f16x8*)(Wl + l15 * 264 + (kc * 4 + qd) * 8);
        }
        return;
    }

    // ---- X fragment pack + v12 ----
    f16x8* VfH = (f16x8*)(psmem + PVH_OFF);
    f16x8* VfL = (f16x8*)(psmem + PVL_OFF);
    f32x4* Pp  = (f32x4*)(psmem + PP_OFF);

    const int b = blk - 128;
    const float* xb = texts + (size_t)b * NF * ED;

    #pragma unroll
    for (int i0 = 0; i0 < 2; ++i0) {
        int i = t + i0 * 256;
        int kc = (i >> 6) & 7, ln = i & 63;
        int q = ln >> 4, col = ln & 15;
        int which = col >> 3, kk = col & 7;
        const float* src  = (which ? V2w : V1w) + kk * 256 + kc * 32 + q * 8;
        const float* srcb = Wb + kk * 256 + kc * 32 + q * 8;
        f16x8 hi, lo;
        #pragma unroll
        for (int j = 0; j < 8; ++j) {
            float sv = src[j] + (which ? srcb[j] : 0.f);
            sv *= 16.0f;
            f16 h = (f16)sv;
            hi[j] = h;
            lo[j] = (f16)(sv - (float)h);
        }
        VfH[i] = hi;
        VfL[i] = lo;
    }

    f16x8 FH[6], FL[6];
    #pragma unroll
    for (int i0 = 0; i0 < 6; ++i0) {
        int i = t + i0 * 256;
        int rt = i >> 9, kc = (i >> 6) & 7;
        int q = lane >> 4, l15 = lane & 15;
        int row = rt * 16 + l15;
        f16x8 hi, lo;
        if (row < NF) {
            const float* s = xb + row * ED + kc * 32 + q * 8;
            float4 a = *(const float4*)s;
            float4 c = *(const float4*)(s + 4);
            float v[8] = {a.x, a.y, a.z, a.w, c.x, c.y, c.z, c.w};
            #pragma unroll
            for (int j = 0; j < 8; ++j) {
                f16 h = (f16)v[j];
                hi[j] = h;
                lo[j] = (f16)(v[j] - (float)h);
            }
        } else {
            #pragma unroll
            for (int j = 0; j < 8; ++j) { hi[j] = (f16)0.f; lo[j] = (f16)0.f; }
        }
        FH[i0] = hi;
        FL[i0] = lo;
        XfH[(size_t)b * NFRAG + i] = hi;
    }
    __syncthreads();

    f32x4 pacc[3];
    #pragma unroll
    for (int rt = 0; rt < 3; ++rt) pacc[rt] = (f32x4){0.f, 0.f, 0.f, 0.f};
    #pragma unroll
    for (int rt = 0; rt < 3; ++rt) {
        #pragma unroll
        for (int s = 0; s < 2; ++s) {
            const int i0 = rt * 2 + s;
            const int kc = wave + 4 * s;
            f16x8 bh = VfH[kc * 64 + lane];
            f16x8 bl = VfL[kc * 64 + lane];
            pacc[rt] = mfma16(FH[i0], bh, pacc[rt]);
            pacc[rt] = mfma16(FH[i0], bl, pacc[rt]);
            pacc[rt] = mfma16(FL[i0], bh, pacc[rt]);
        }
    }
    #pragma unroll
    for (int rt = 0; rt < 3; ++rt)
        Pp[(wave * 3 + rt) * 64 + lane] = pacc[rt];
    __syncthreads();

    if (wave < 3) {
        f32x4 acc = Pp[(0 * 3 + wave) * 64 + lane];
        #pragma unroll
        for (int w = 1; w < 4; ++w) acc += Pp[(w * 3 + wave) * 64 + lane];
        const int q = lane >> 4, l15 = lane & 15;
        const int which = l15 >> 3, kk = l15 & 7;
        const float bias = which ? V2b[kk] : V1b[kk];
        #pragma unroll
        for (int r = 0; r < 4; ++r) {
            const int n = wave * 16 + q * 4 + r;
            if (n < NF)
                v12[((size_t)b * 16 + l15) * NF + n] = acc[r] * 0.0625f + bias;
        }
    }
}

// P1 step (shared X, both k's, swapped operands): 12 MFMA per kc.
#define P1S(ACC, H, KC) do {                                                  \
    f16x8 w00_ = Wk0[((((H) * 8 + wave) * 8) + (KC)) * 64 + lane];            \
    f16x8 w01_ = Wk0[((((H) * 8 + wave + 4) * 8) + (KC)) * 64 + lane];        \
    f16x8 w10_ = Wk1[((((H) * 8 + wave) * 8) + (KC)) * 64 + lane];            \
    f16x8 w11_ = Wk1[((((H) * 8 + wave + 4) * 8) + (KC)) * 64 + lane];        \
    _Pragma("unroll")                                                         \
    for (int rt_ = 0; rt_ < 3; ++rt_) {                                       \
        f16x8 ah_ = *xfragp(smem, rt_ * 8 + (KC), lane);                      \
        ACC[rt_][0][0] = mfma16(w00_, ah_, ACC[rt_][0][0]);                   \
        ACC[rt_][1][0] = mfma16(w01_, ah_, ACC[rt_][1][0]);                   \
        ACC[rt_][0][1] = mfma16(w10_, ah_, ACC[rt_][0][1]);                   \
        ACC[rt_][1][1] = mfma16(w11_, ah_, ACC[rt_][1][1]);                   \
    }                                                                         \
} while (0)

// P2 tile-pair: one Xh read feeds BOTH k's Wxh buffers (8 MFMA / 12 reads).
#define P2_TILE2(IT, H) do {                                                  \
    const int p_ = wave + (IT) * 4;                                           \
    if (p_ < 9) {                                                             \
        const int nt_ = p_ / 3, mt_ = p_ % 3;                                 \
        const int row_ = nt_ * 16 + l15;                                      \
        const int cr_ = row_ > 35 ? 35 : row_;   /* clamp: rows 36+ unused */ \
        const f16* w0p_ = Wxh0 + cr_ * WXSTR + quad * 8;                      \
        const f16* w1p_ = Wxh1 + cr_ * WXSTR + quad * 8;                      \
        _Pragma("unroll")                                                     \
        for (int kc2_ = 0; kc2_ < 4; ++kc2_) {                                \
            f16x8 xb_ = *xfragp(smem, mt_ * 8 + (H) * 4 + kc2_, lane);        \
            f16x8 a0_ = *(const f16x8*)(w0p_ + kc2_ * 32);                    \
            f16x8 a1_ = *(const f16x8*)(w1p_ + kc2_ * 32);                    \
            sacc[0][IT] = mfma16(a0_, xb_, sacc[0][IT]);                      \
            sacc[1][IT] = mfma16(a1_, xb_, sacc[1][IT]);                      \
        }                                                                     \
    }                                                                         \
} while (0)

#define ZERO_ACC(ACC) do {                                                    \
    _Pragma("unroll")                                                         \
    for (int i_ = 0; i_ < 3; ++i_)                                            \
        _Pragma("unroll")                                                     \
        for (int j_ = 0; j_ < 2; ++j_) {                                      \
            ACC[i_][j_][0] = (f32x4){0.f, 0.f, 0.f, 0.f};                     \
            ACC[i_][j_][1] = (f32x4){0.f, 0.f, 0.f, 0.f};                     \
        }                                                                     \
} while (0)

// packed f16x4 stores of both k's Wx half; rows 36-47 skipped (rt2 l15>=4).
#define STORE_WX2(ACC) do {                                                   \
    _Pragma("unroll")                                                         \
    for (int rt_ = 0; rt_ < 3; ++rt_) {                                       \
        const int n_ = rt_ * 16 + l15;                                        \
        if (rt_ < 2 || l15 < 4) {                                             \
            _Pragma("unroll")                                                 \
            for (int j2_ = 0; j2_ < 2; ++j2_) {                               \
                const int cb_ = (j2_ ? (wave + 4) : wave) * 16 + quad * 4;    \
                f16x4 h0_, h1_;                                               \
                _Pragma("unroll")                                             \
                for (int r_ = 0; r_ < 4; ++r_) {                              \
                    h0_[r_] = (f16)(ACC[rt_][j2_][0][r_]);                    \
                    h1_[r_] = (f16)(ACC[rt_][j2_][1][r_]);                    \
                }                                                             \
                *(f16x4*)(Wxh0 + n_ * WXSTR + cb_) = h0_;                     \
                *(f16x4*)(Wxh1 + n_ * WXSTR + cb_) = h1_;                     \
            }                                                                 \
        }                                                                     \
    }                                                                         \
} while (0)

// k-pair main: shared-X P1 (acc[3][2][2]) + dual compact Wxh buffers.
// Pipeline (5 barriers): stage; P1(h0); store both; bar;
// [P2(h0,k0)+P2(h0,k1) || P1(h1)]; bar; store both; bar; P2(h1) tail; epilogue.
__global__ __launch_bounds__(256, 4) void ntn_main(
    const f16x8* __restrict__ XfHG,
    const f16x8* __restrict__ WfH,
    const float* __restrict__ v12,
    const float* __restrict__ Uw, const float* __restrict__ Ubp,
    float* __restrict__ out)
{
    extern __shared__ char smem[];
    f16*   Wxh0 = (f16*)(smem + WX0_OFF);
    f16*   Wxh1 = (f16*)(smem + WX1_OFF);
    float* v1s2 = (float*)(smem + V_OFF);      // [2][36], pre-scaled by 2*log2e
    float* v2s2 = v1s2 + 72;                   // [2][36]
    float* Uws  = v1s2 + 144;                  // [9]
    float* Ls   = v1s2 + 153;                  // [324] logits

    const int id  = blockIdx.x;
    const int xcd = id & 7;
    const int rem = id >> 3;
    const int kp  = rem & 3;
    const int b   = ((rem >> 2) << 3) | xcd;
    const int k0  = kp * 2;

    const int t    = threadIdx.x;
    const int wave = t >> 6;
    const int lane = t & 63;
    const int quad = lane >> 4;
    const int l15  = lane & 15;

    // ---- stage X-hi fragments (rt0,1 linear; rt2 compact; zero block) ----
    {
        const f16x8* gh = XfHG + (size_t)b * NFRAG;
        #pragma unroll
        for (int i0 = 0; i0 < 4; ++i0)
            *(f16x8*)(smem + (size_t)(t + i0 * 256) * 16) = gh[t + i0 * 256];
        #pragma unroll
        for (int i0 = 4; i0 < 6; ++i0) {
            const int e = t + i0 * 256;
            f16x8 v = gh[e];
            const int kc = (e >> 6) - 16;
            if (l15 < 4)
                *(f16x8*)(smem + XC2_OFF + (size_t)(kc * 16 + quad * 4 + l15) * 16) = v;
        }
        if (t == 0) {
            f16x8 z;
            #pragma unroll
            for (int j = 0; j < 8; ++j) z[j] = (f16)0.f;
            *(f16x8*)(smem + ZB_OFF) = z;
        }
    }
    if (t < 144) {
        const int r = t / 36, n = t - r * 36;
        const int which = r & 1, kq = r >> 1;
        float v = v12[((size_t)b * 16 + which * 8 + (k0 + kq)) * NF + n] * TWO_LOG2E;
        (which ? v2s2 : v1s2)[kq * 36 + n] = v;
    }
    if (t < 8) Uws[t] = Uw[t];
    if (t == 8) Uws[8] = Ubp[0];
    __syncthreads();   // (0)

    const f16x8* Wk0 = WfH + (size_t)k0 * 8192;
    const f16x8* Wk1 = Wk0 + 8192;

    f32x4 sacc[2][3];
    #pragma unroll
    for (int kk = 0; kk < 2; ++kk)
        #pragma unroll
        for (int it = 0; it < 3; ++it) sacc[kk][it] = (f32x4){0.f, 0.f, 0.f, 0.f};

    f32x4 acc[3][2][2];

    // ===== P1(h0), both k's =====
    ZERO_ACC(acc);
    #pragma unroll
    for (int kc = 0; kc < 8; ++kc) P1S(acc, 0, kc);
    STORE_WX2(acc);              // Wxh unread so far
    __syncthreads();             // (1) Wx(h0) visible

    // ===== fat region: [P2(h0,k0)+P2(h0,k1)] interleaved with P1(h1) =====
    ZERO_ACC(acc);
    #pragma unroll
    for (int kc = 0; kc < 8; ++kc) {
        P1S(acc, 1, kc);
        if (kc == 1) P2_TILE2(0, 0);
        if (kc == 3) P2_TILE2(1, 0);
        if (kc == 5) P2_TILE2(2, 0);
    }
    __syncthreads();             // (2) all h0 Wxh reads done
    STORE_WX2(acc);
    __syncthreads();             // (3) Wx(h1) visible

    // ===== tail: P2(h1), both k's =====
    P2_TILE2(0, 1);
    P2_TILE2(1, 1);
    P2_TILE2(2, 1);

    // ===== epilogue: T = tanh(S + v1 + v2) -> Ts (overlays Wxh0/1) =====
    __syncthreads();             // (4)
    float* Ts = (float*)Wxh0;    // padded addr = idx + (idx>>3); 11656B <= 19584B
    #pragma unroll
    for (int kk = 0; kk < 2; ++kk)
        #pragma unroll
        for (int it = 0; it < 3; ++it) {
            const int p = wave + it * 4;
            if (p < 9) {
                const int nt = p / 3, mt = p % 3;
                const int m = mt * 16 + l15;
                if (m < NF) {
                    #pragma unroll
                    for (int r = 0; r < 4; ++r) {
                        const int n = nt * 16 + quad * 4 + r;
                        if (n < NF) {
                            float x = sacc[kk][it][r] * C1F
                                      + v1s2[kk * 36 + n] + v2s2[kk * 36 + m];
                            float e = exp2f(x);
                            const int idx = kk * NN2 + n * NF + m;
                            Ts[idx + (idx >> 3)] = 1.f - 2.f / (e + 1.f);
                        }
                    }
                }
            }
        }
    __syncthreads();
    #pragma unroll
    for (int u0 = 0; u0 < 2; ++u0) {
        const int u = t + u0 * 256;
        if (u < 324) {
            const float* tp = Ts + u * 9;
            float lg = Uws[8];
            #pragma unroll
            for (int j = 0; j < 8; ++j) lg += Uws[j] * tp[j];
            Ls[u] = lg;
        }
    }
    __syncthreads();
    #pragma unroll
    for (int rr0 = 0; rr0 < 3; ++rr0) {
        const int rr = wave + rr0 * 4;
        if (rr < 9) {
            float v = (lane < NF) ? Ls[rr * 36 + lane] : -INFINITY;
            float mx = v;
            #pragma unroll
            for (int off = 32; off > 0; off >>= 1) mx = fmaxf(mx, __shfl_xor(mx, off));
            float e = (lane < NF) ? __expf(v - mx) : 0.f;
            float sm = e;
            #pragma unroll
            for (int off = 32; off > 0; off >>= 1) sm += __shfl_xor(sm, off);
            if (lane < NF)
                out[(size_t)b * NN2 + kp * 324 + rr * 36 + lane] = e / sm;
        }
    }
}

extern "C" void kernel_launch(void* const* d_in, const int* in_sizes, int n_in,
                              void* d_out, int out_size, void* d_ws, size_t ws_size,
                              hipStream_t stream) {
    const float* texts = (const float*)d_in[0];
    const float* W     = (const float*)d_in[1];
    const float* Wb    = (const float*)d_in[2];
    const float* V1w   = (const float*)d_in[3];
    const float* V1b   = (const float*)d_in[4];
    const float* V2w   = (const float*)d_in[5];
    const float* V2b   = (const float*)d_in[6];
    const float* Uw    = (const float*)d_in[7];
    const float* Ub    = (const float*)d_in[8];

    char* ws = (char*)d_ws;
    f16x8* WfH = (f16x8*)ws;                                   //  1 MiB
    f16x8* XfH = (f16x8*)(ws + (1 << 20));                     // 24 MiB
    float* v12 = (float*)(ws + (1 << 20) + (size_t)NB * NFRAG * 16);   // 2.25 MiB
    float* outp = (float*)d_out;

    hipFuncSetAttribute((const void*)prep_all,
                        hipFuncAttributeMaxDynamicSharedMemorySize, SMEM_PREP);
    hipFuncSetAttribute((const void*)ntn_main,
                        hipFuncAttributeMaxDynamicSharedMemorySize, SMEM_MAIN);

    prep_all<<<128 + NB, 256, SMEM_PREP, stream>>>(W, WfH, texts, XfH,
                                                   V1w, V1b, V2w, V2b, Wb, v12);
    ntn_main<<<NB * NK / 2, 256, SMEM_MAIN, stream>>>(XfH, WfH, v12, Uw, Ub, outp);
}